// Round 6
// baseline (4362.317 us; speedup 1.0000x reference)
//
#include <hip/hip_runtime.h>
#include <stdint.h>

// ---------------------------------------------------------------------------
// Binary net, single persistent kernel + tiny init node.
//   conv path (blocks 0..383):  conv0 -> pack_h0 -> conv1 -> bn1 -> pack_a0
//   weight path (blocks 384..511): stream-pack fw0 (401MB) -> wp   [overlaps!]
//   join: popcount GEMM (512 tiles) -> fc0 epilogue -> fc1
// Co-residency: grid 512, launch_bounds(256,4) => <=128 VGPR, 32KB LDS
//   => >=4 blocks/CU capacity on 256 CUs (1024) >= 512  -> no deadlock.
// Barriers: per-site monotonic counters zeroed by k_init each call.
// Bit order: word j=4Q+c holds elements k=256Q+4i+c at bit i (both operands).
// ---------------------------------------------------------------------------

static constexpr int BATCH = 256;
static constexpr int K0    = 100352;   // 128*784
static constexpr int KW    = 1568;     // K0/64
static constexpr int N1    = 1024;
static constexpr int KS    = 16;       // fc0 k-splits
static constexpr int JW    = 98;       // KW/KS
static constexpr int SUB   = 14;       // ap words per LDS subchunk
static constexpr int NS    = 7;        // JW/SUB
static constexpr unsigned ZCAP = 65536;
static constexpr int NBLK  = 512;
static constexpr int NC    = 384;      // conv-path blocks
__device__ __forceinline__ float fsign(float v){
    return (v > 0.f) ? 1.f : ((v < 0.f) ? -1.f : 0.f);
}

__device__ __forceinline__ void gbar(unsigned* c, unsigned goal)
{
    __threadfence();
    __syncthreads();
    if (threadIdx.x == 0) {
        unsigned prev = __hip_atomic_fetch_add(c, 1u, __ATOMIC_ACQ_REL,
                                               __HIP_MEMORY_SCOPE_AGENT);
        if (prev + 1u < goal) {
            while (__hip_atomic_load(c, __ATOMIC_ACQUIRE,
                                     __HIP_MEMORY_SCOPE_AGENT) < goal)
                __builtin_amdgcn_s_sleep(8);
        }
    }
    __syncthreads();
    __threadfence();
}

__global__ void k_init(unsigned* p)
{
    if (threadIdx.x < 16) p[threadIdx.x] = 0;   // 7 barrier ctrs + zcnt
}

__global__ __launch_bounds__(256, 4) void k_mega(
    const float* __restrict__ x,   const float* __restrict__ cw0,
    const float* __restrict__ cp0, const float* __restrict__ cg0,
    const float* __restrict__ cb0, const float* __restrict__ cw1,
    const float* __restrict__ cp1, const float* __restrict__ cg1,
    const float* __restrict__ cb1, const float* __restrict__ fw0,
    const float* __restrict__ fp0, const float* __restrict__ fg0,
    const float* __restrict__ fb0, const float* __restrict__ fw1,
    const float* __restrict__ fp1, const float* __restrict__ fg1,
    const float* __restrict__ fb1, const float* __restrict__ scale,
    unsigned* ctr, unsigned* zcnt, uint64_t* __restrict__ zlist,
    double* __restrict__ pS0, double* __restrict__ pQ0,
    double* __restrict__ pS1, double* __restrict__ pQ1,
    double* __restrict__ A1B1,
    int8_t* __restrict__ h0s, uint64_t* __restrict__ hp,
    int16_t* __restrict__ h1s, uint64_t* __restrict__ ap_t,
    uint64_t* __restrict__ wn1, uint64_t* __restrict__ wnz1,
    uint64_t* __restrict__ wp, int16_t* __restrict__ pcpart,
    float* __restrict__ af, float* __restrict__ out)
{
    __shared__ __align__(16) char smem[32768];
    const int bid  = blockIdx.x;
    const int tid  = threadIdx.x;
    const int wv   = tid >> 6;
    const int lane = tid & 63;

    if (bid < NC) {
        // ============================ conv path ============================
        if (bid < 256) {
            // ---- conv0 for image bid ----
            float (*img)[30]  = (float(*)[30])smem;
            float (*redS)[64] = (float(*)[64])(smem + 3616);
            float (*redQ)[64] = (float(*)[64])(smem + 3616 + 1024);
            const int b = bid;
            for (int i = tid; i < 900; i += 256) ((float*)img)[i] = 0.f;
            __syncthreads();
            for (int i = tid; i < 784; i += 256) {
                float v = x[b*784 + i];
                img[1 + i/28][1 + i%28] = fsign(v);
            }
            __syncthreads();
            float wsg[9];
            #pragma unroll
            for (int t = 0; t < 9; t++) wsg[t] = fsign(cw0[lane*9 + t]);
            float a = cp0[lane];
            float accS = 0.f, accQ = 0.f;
            for (int i = 0; i < 196; i++) {
                int p = wv*196 + i;
                int y = p / 28, xx = p % 28;
                float s = 0.f;
                #pragma unroll
                for (int dy = 0; dy < 3; dy++)
                    #pragma unroll
                    for (int dx = 0; dx < 3; dx++)
                        s += img[y+dy][xx+dx] * wsg[dy*3+dx];
                h0s[(size_t)(b*784 + p)*64 + lane] = (int8_t)(int)s;
                float v = (s >= 0.f) ? s : a*s;
                accS += v; accQ += v*v;
            }
            redS[wv][lane] = accS; redQ[wv][lane] = accQ;
            __syncthreads();
            if (tid < 64) {
                double s = (double)redS[0][tid] + redS[1][tid] + redS[2][tid] + redS[3][tid];
                double q = (double)redQ[0][tid] + redQ[1][tid] + redQ[2][tid] + redQ[3][tid];
                pS0[tid*256 + b] = s;
                pQ0[tid*256 + b] = q;
            }
        } else if (bid < 288) {
            // ---- pack conv1 weights (32 blocks x 36 units) ----
            int cb = bid - 256;
            for (int it = 0; it < 9; ++it) {
                int idx = cb*36 + it*4 + wv;           // (oc*9 + t), 0..1151
                int oc = idx / 9, t = idx - oc*9;
                float w = cw1[oc*576 + lane*9 + t];
                uint64_t nm = __ballot(w < 0.f);
                uint64_t zm = __ballot(w != 0.f);
                if (lane == 0) { wn1[idx] = nm; wnz1[idx] = zm; }
            }
        }
        gbar(&ctr[0], NC);

        // ---- pack_h0: per-block LUT from pS0, then pack hp ----
        {
            unsigned* l = (unsigned*)smem;
            if (tid < 64) {
                double s0 = 0, s1 = 0, q0 = 0, q1 = 0;
                for (int b2 = 0; b2 < 256; b2 += 2) {
                    s0 += pS0[tid*256 + b2];   s1 += pS0[tid*256 + b2 + 1];
                    q0 += pQ0[tid*256 + b2];   q1 += pQ0[tid*256 + b2 + 1];
                }
                double S = s0 + s1, Q = q0 + q1;
                double mean = S * (1.0/200704.0);
                double var  = Q * (1.0/200704.0) - mean*mean;
                if (var < 0.0) var = 0.0;
                double A = (double)cg0[tid] / sqrt(var + 1e-5);
                double B = (double)cb0[tid] - mean*A;
                float a = cp0[tid];
                unsigned m = 0;
                for (int s = -9; s <= 9; ++s) {
                    float v = (s >= 0) ? (float)s : a*(float)s;
                    if (fma((double)v, A, B) < 0.0) m |= 1u << (s + 9);
                }
                l[tid] = m;
            }
            __syncthreads();
            for (int u = bid; u < 784; u += NC) {
                int pixel = u*256 + tid;
                const int4* p4 = (const int4*)(h0s + (size_t)pixel*64);
                int4 va = p4[0], vb = p4[1], vc = p4[2], vd = p4[3];
                int wa[16] = {va.x,va.y,va.z,va.w, vb.x,vb.y,vb.z,vb.w,
                              vc.x,vc.y,vc.z,vc.w, vd.x,vd.y,vd.z,vd.w};
                unsigned lo = 0, hi = 0;
                #pragma unroll
                for (int wi = 0; wi < 16; ++wi) {
                    unsigned w = (unsigned)wa[wi];
                    #pragma unroll
                    for (int c2 = 0; c2 < 4; ++c2) {
                        int ch = wi*4 + c2;
                        int s = (int)(signed char)(w >> (8*c2));
                        unsigned bit = (l[ch] >> (s + 9)) & 1u;
                        if (ch < 32) lo |= bit << ch; else hi |= bit << (ch - 32);
                    }
                }
                hp[pixel] = ((uint64_t)hi << 32) | lo;
            }
        }
        gbar(&ctr[1], NC);

        // ---- conv1 via XOR/popcount, race-free bn1 partials ----
        {
            float (*lS)[8] = (float(*)[8])smem;
            float (*lQ)[8] = (float(*)[8])(smem + 128);
            for (int u = bid; u < 16384; u += NC) {
                int ocg = u & 15, ptg = (u >> 4) & 3, b = u >> 6;
                int pt = ptg*4 + wv;
                bool active = (pt < 13);
                int p = active ? (pt*64 + lane) : 0;
                bool pvalid = active && (p < 784);
                int y = p / 28, xx = p % 28;
                uint64_t nb[9]; unsigned vmask = 0;
                #pragma unroll
                for (int dy = 0; dy < 3; dy++)
                    #pragma unroll
                    for (int dx = 0; dx < 3; dx++) {
                        int t = dy*3+dx;
                        int yy = y + dy - 1, xv = xx + dx - 1;
                        bool ok = (yy >= 0 && yy < 28 && xv >= 0 && xv < 28);
                        nb[t] = hp[b*784 + (ok ? (yy*28+xv) : 0)];
                        if (ok) vmask |= 1u << t;
                    }
                #pragma unroll
                for (int o = 0; o < 8; o++) {
                    int oc = ocg*8 + o;
                    int base = oc*9;
                    int acc = 0;
                    #pragma unroll
                    for (int t = 0; t < 9; t++) {
                        uint64_t wn = wn1[base+t], wz = wnz1[base+t];
                        if (vmask & (1u<<t))
                            acc += (int)__popcll(wz) - 2*(int)__popcll((nb[t] ^ wn) & wz);
                    }
                    if (pvalid) h1s[((size_t)b*128 + oc)*784 + p] = (int16_t)acc;
                    float pr = cp1[oc];
                    float v = pvalid ? ((acc >= 0) ? (float)acc : pr*(float)acc) : 0.f;
                    float s = v, q = v*v;
                    #pragma unroll
                    for (int off = 32; off; off >>= 1) {
                        s += __shfl_xor(s, off);
                        q += __shfl_xor(q, off);
                    }
                    if (lane == 0) { lS[wv][o] = s; lQ[wv][o] = q; }
                }
                __syncthreads();
                if (tid < 16) {
                    int o = tid & 7;
                    bool isQ = tid >= 8;
                    double v4 = isQ ? ((double)lQ[0][o] + lQ[1][o] + lQ[2][o] + lQ[3][o])
                                    : ((double)lS[0][o] + lS[1][o] + lS[2][o] + lS[3][o]);
                    double* dst = isQ ? pQ1 : pS1;
                    dst[(size_t)(ocg*8 + o)*1024 + (b*4 + ptg)] = v4;
                }
                __syncthreads();
            }
        }
        gbar(&ctr[2], NC);

        // ---- bn1 finalize ----
        if (bid < 128) {
            double* rs = (double*)smem;
            double* rq = rs + 256;
            int oc = bid;
            double s = 0.0, q = 0.0;
            #pragma unroll
            for (int i = 0; i < 4; ++i) {
                s += pS1[(size_t)oc*1024 + tid + 256*i];
                q += pQ1[(size_t)oc*1024 + tid + 256*i];
            }
            rs[tid] = s; rq[tid] = q;
            __syncthreads();
            for (int off = 128; off; off >>= 1) {
                if (tid < off) { rs[tid] += rs[tid+off]; rq[tid] += rq[tid+off]; }
                __syncthreads();
            }
            if (tid == 0) {
                double mean = rs[0] * (1.0/200704.0);
                double var  = rq[0] * (1.0/200704.0) - mean*mean;
                if (var < 0.0) var = 0.0;
                double A = (double)cg1[oc] / sqrt(var + 1e-5);
                A1B1[oc] = A; A1B1[128 + oc] = (double)cb1[oc] - mean*A;
            }
        }
        gbar(&ctr[3], NC);

        // ---- pack fc0 activations ----
        {
            int gw = bid*4 + wv;
            for (int u = gw; u < 100352; u += NC*4) {
                int b = u / 392, q = u - b*392;
                int k0 = q*256 + lane*4;
                short4 sv4 = *(const short4*)(h1s + (size_t)b*K0 + k0);
                int oc = k0 / 784;
                double A = A1B1[oc], B = A1B1[128 + oc];
                float aa = cp1[oc];
                int ss[4] = {sv4.x, sv4.y, sv4.z, sv4.w};
                uint64_t words[4];
                #pragma unroll
                for (int c = 0; c < 4; ++c) {
                    float s = (float)ss[c];
                    float v = (s >= 0.f) ? s : aa*s;
                    double t = fma((double)v, A, B);
                    words[c] = __ballot(t < 0.0);
                }
                if (lane == 0) {
                    #pragma unroll
                    for (int c = 0; c < 4; ++c)
                        ap_t[(size_t)(4*q + c)*256 + b] = words[c];
                }
            }
        }
    } else {
        // ============================ weight path ============================
        int wid = bid - NC;                 // 0..127
        int n0w = wid*8;
        for (int r = 0; r < 2; ++r) {
            int n = n0w + wv*2 + r;
            const float* src = fw0 + (size_t)n*K0 + lane*4;
            uint64_t* dst = wp + (size_t)n*KW;
            for (int it = 0; it < 392; it += 14) {      // 14 loads in flight
                float4 f[14];
                #pragma unroll
                for (int u2 = 0; u2 < 14; ++u2)
                    f[u2] = *(const float4*)(src + (size_t)(it+u2)*256);
                #pragma unroll
                for (int u2 = 0; u2 < 14; ++u2) {
                    int g = it + u2;
                    uint64_t g0 = __ballot(f[u2].x < 0.f);
                    uint64_t g1 = __ballot(f[u2].y < 0.f);
                    uint64_t g2 = __ballot(f[u2].z < 0.f);
                    uint64_t g3 = __ballot(f[u2].w < 0.f);
                    uint64_t z0 = __ballot(f[u2].x == 0.f);
                    uint64_t z1 = __ballot(f[u2].y == 0.f);
                    uint64_t z2 = __ballot(f[u2].z == 0.f);
                    uint64_t z3 = __ballot(f[u2].w == 0.f);
                    if (lane == 0) {
                        ulonglong2 a{g0, g1}, b2{g2, g3};
                        *(ulonglong2*)(dst + g*4)     = a;
                        *(ulonglong2*)(dst + g*4 + 2) = b2;
                        if (z0 | z1 | z2 | z3) {        // essentially never
                            uint64_t zz[4] = {z0, z1, z2, z3};
                            #pragma unroll
                            for (int c = 0; c < 4; ++c) if (zz[c]) {
                                unsigned id = atomicAdd(zcnt, 1u);
                                if (id < ZCAP) {
                                    zlist[2*id]   = ((uint64_t)(unsigned)n << 32)
                                                  | (unsigned)(4*g + c);
                                    zlist[2*id+1] = zz[c];
                                }
                            }
                        }
                    }
                }
            }
        }
    }
    gbar(&ctr[4], NBLK);       // JOIN: ap_t, wp, wn/wnz, zlist all ready

    // ============================ fc0 GEMM ============================
    {
        uint64_t (*apL)[256] = (uint64_t(*)[256])smem;          // 28672 B
        uint64_t (*wTc)[14]  = (uint64_t(*)[14])(smem + 28672); //  3584 B
        int nt = bid & 31, ks = bid >> 5;     // 32 n-tiles x 16 k-splits
        int n0 = nt*32, j0 = ks*JW;
        int bq = tid & 31, nq = tid >> 5;
        int pc[8][4];
        #pragma unroll
        for (int i = 0; i < 8; i++)
            #pragma unroll
            for (int k = 0; k < 4; k++) pc[i][k] = 0;
        for (int c = 0; c < NS; ++c) {
            int jb = j0 + c*SUB;
            #pragma unroll
            for (int r = 0; r < SUB; ++r)
                apL[r][tid] = ap_t[(size_t)(jb + r)*256 + tid];
            if (tid < 224) {
                int row = tid / 7, wi = tid - row*7;
                ulonglong2 v = *(const ulonglong2*)(wp + (size_t)(n0+row)*KW + jb + wi*2);
                wTc[row][wi*2] = v.x; wTc[row][wi*2+1] = v.y;
            }
            __syncthreads();
            #pragma unroll
            for (int jj = 0; jj < SUB; ++jj) {
                uint64_t aw[8], ww[4];
                #pragma unroll
                for (int i = 0; i < 8; i++) aw[i] = apL[jj][bq + 32*i];
                #pragma unroll
                for (int k = 0; k < 4; k++) ww[k] = wTc[nq + 8*k][jj];
                #pragma unroll
                for (int i = 0; i < 8; i++)
                    #pragma unroll
                    for (int k = 0; k < 4; k++)
                        pc[i][k] += (int)__popcll(aw[i] ^ ww[k]);
            }
            __syncthreads();
        }
        #pragma unroll
        for (int k = 0; k < 4; k++) {
            int n = n0 + nq + 8*k;
            #pragma unroll
            for (int i = 0; i < 8; i++)
                pcpart[((size_t)ks*N1 + n)*BATCH + (bq + 32*i)] = (int16_t)pc[i][k];
        }
    }
    gbar(&ctr[5], NBLK);

    // ============================ fc0 epilogue ============================
    {
        double* rs  = (double*)smem;
        double* rq  = rs + 256;
        double* AB2 = rq + 256;
        for (int n = bid; n < N1; n += NBLK) {
            int b = tid;
            int pcs = 0;
            #pragma unroll
            for (int ks = 0; ks < KS; ks++)
                pcs += (int)pcpart[((size_t)ks*N1 + n)*BATCH + b];
            int s = K0 - 2*pcs;
            unsigned cnt = *zcnt; if (cnt > ZCAP) cnt = ZCAP;
            for (unsigned e = 0; e < cnt; ++e) {
                uint64_t key = zlist[2*e];
                if ((int)(key >> 32) == n) {
                    uint64_t zm = zlist[2*e+1];
                    uint64_t a = ap_t[(size_t)(key & 0xffffffffu)*256 + b];
                    s += 2*(int)__popcll(a & zm) - (int)__popcll(zm);
                }
            }
            float a = fp0[n];
            float v = (s >= 0) ? (float)s : a*(float)s;
            rs[b] = v; rq[b] = (double)v*(double)v;
            __syncthreads();
            for (int off = 128; off > 0; off >>= 1) {
                if (b < off) { rs[b] += rs[b+off]; rq[b] += rq[b+off]; }
                __syncthreads();
            }
            if (b == 0) {
                double mean = rs[0] / 256.0;
                double var  = rq[0] / 256.0 - mean*mean;
                if (var < 0.0) var = 0.0;
                double A = (double)fg0[n] / sqrt(var + 1e-5);
                AB2[0] = A; AB2[1] = (double)fb0[n] - mean*A;
            }
            __syncthreads();
            double t = fma((double)v, AB2[0], AB2[1]);
            af[(size_t)n*256 + b] = (t > 0.0) ? 1.f : ((t < 0.0) ? -1.f : 0.f);
            __syncthreads();
        }
    }
    gbar(&ctr[6], NBLK);

    // ============================ fc1 + bn + scale ============================
    if (bid < 10) {
        double* sv  = (double*)smem;
        double* ABj = sv + 256;
        int j = bid, b = tid;
        float acc = 0.f;
        for (int k = 0; k < 1024; ++k)
            acc += af[(size_t)k*256 + b] * fsign(fw1[j*1024 + k]);
        float a = fp1[j];
        float v = (acc >= 0.f) ? acc : a*acc;
        sv[b] = (double)v;
        __syncthreads();
        for (int off = 128; off > 0; off >>= 1) {
            if (b < off) sv[b] += sv[b+off];
            __syncthreads();
        }
        double mean = sv[0] / 256.0;
        __syncthreads();
        double d = (double)v - mean;
        sv[b] = d*d;
        __syncthreads();
        for (int off = 128; off > 0; off >>= 1) {
            if (b < off) sv[b] += sv[b+off];
            __syncthreads();
        }
        if (b == 0) {
            double var = sv[0] / 256.0;
            double A = (double)fg1[j] / sqrt(var + 1e-5);
            ABj[0] = A; ABj[1] = (double)fb1[j] - mean*A;
        }
        __syncthreads();
        out[b*10 + j] = (float)fma((double)v, ABj[0], ABj[1]) * scale[0];
    }
}

extern "C" void kernel_launch(void* const* d_in, const int* in_sizes, int n_in,
                              void* d_out, int out_size, void* d_ws, size_t ws_size,
                              hipStream_t stream)
{
    const float* x    = (const float*)d_in[0];
    const float* cw0  = (const float*)d_in[1];
    const float* cp0  = (const float*)d_in[2];
    const float* cg0  = (const float*)d_in[3];
    const float* cb0  = (const float*)d_in[4];
    const float* cw1  = (const float*)d_in[5];
    const float* cp1  = (const float*)d_in[6];
    const float* cg1  = (const float*)d_in[7];
    const float* cb1  = (const float*)d_in[8];
    const float* fw0  = (const float*)d_in[9];
    const float* fp0  = (const float*)d_in[10];
    const float* fg0  = (const float*)d_in[11];
    const float* fb0  = (const float*)d_in[12];
    const float* fw1  = (const float*)d_in[13];
    const float* fp1  = (const float*)d_in[14];
    const float* fg1  = (const float*)d_in[15];
    const float* fb1  = (const float*)d_in[16];
    const float* scale= (const float*)d_in[17];

    char* ws = (char*)d_ws;
    size_t off = 0;
    auto alloc = [&](size_t bytes)->char* {
        char* r = ws + off; off = (off + bytes + 255) & ~(size_t)255; return r; };

    unsigned* ctrz  = (unsigned*)alloc(256);        // ctr[0..7] + zcnt @ words 0..8
    unsigned* ctr   = ctrz;
    unsigned* zcnt  = ctrz + 8;
    double*   pS0   = (double*)alloc((size_t)64*256*8);
    double*   pQ0   = (double*)alloc((size_t)64*256*8);
    double*   pS1   = (double*)alloc((size_t)128*1024*8);
    double*   pQ1   = (double*)alloc((size_t)128*1024*8);
    double*   A1B1  = (double*)alloc(256*8);
    int8_t*   h0s   = (int8_t*)alloc((size_t)256*784*64);
    uint64_t* hp    = (uint64_t*)alloc((size_t)256*784*8);
    int16_t*  h1s   = (int16_t*)alloc((size_t)256*128*784*2);
    uint64_t* ap_t  = (uint64_t*)alloc((size_t)KW*256*8);
    uint64_t* wn1   = (uint64_t*)alloc(1152*8);
    uint64_t* wnz1  = (uint64_t*)alloc(1152*8);
    uint64_t* wp    = (uint64_t*)alloc((size_t)N1*KW*8);
    int16_t*  pcpart= (int16_t*)alloc((size_t)KS*N1*BATCH*2);
    float*    af    = (float*)alloc((size_t)1024*256*4);
    uint64_t* zlist = (uint64_t*)alloc((size_t)ZCAP*16);
    (void)ws_size; (void)in_sizes; (void)n_in; (void)out_size;

    k_init<<<1, 64, 0, stream>>>(ctrz);
    k_mega<<<NBLK, 256, 0, stream>>>(
        x, cw0, cp0, cg0, cb0, cw1, cp1, cg1, cb1,
        fw0, fp0, fg0, fb0, fw1, fp1, fg1, fb1, scale,
        ctr, zcnt, zlist, pS0, pQ0, pS1, pQ1, A1B1,
        h0s, hp, h1s, ap_t, wn1, wnz1, wp, pcpart, af, (float*)d_out);
}